// Round 2
// baseline (475.726 us; speedup 1.0000x reference)
//
#include <hip/hip_runtime.h>
#include <hip/hip_bf16.h>

#define B_   8
#define S_   1024
#define HID_ 1024
#define NH_  16
#define HD_  64

typedef __bf16 bf16_t;
typedef __bf16 bf16x8 __attribute__((ext_vector_type(8)));
typedef __bf16 bf16x4 __attribute__((ext_vector_type(4)));
typedef float  f32x4  __attribute__((ext_vector_type(4)));

#define MFMA16(a, b, c) __builtin_amdgcn_mfma_f32_16x16x32_bf16(a, b, c, 0, 0, 0)

// ---------------------------------------------------------------------------
// Projection GEMM: C = A @ W^T + bias, A [8192x1024] f32, W [1024x1024] f32.
// z=0: A=query,W=Wk,b=bk -> q_ws[b][h][s][d] (bf16)
// z=1: A=key,  W=Wk,b=bk -> k_ws[b][h][s][d] (bf16)
// z=2: A=value,W=Wv,b=bv -> vt_ws[b][h][d][s] (bf16, transposed for PV B-op)
//
// Reg-staged 2-phase pipeline: issue tile t+1 global loads BEFORE consuming
// tile t's staged regs -> compiler emits counted vmcnt(8), loads stay in
// flight across both barriers (T14-lite; forced reg-staging since we fuse
// the f32->bf16 convert into LDS staging).
// ---------------------------------------------------------------------------
#define BM 128
#define BN 128
#define BK 32
#define LDK 40   // padded LDS row stride in bf16 (80B -> 2-way bank alias, free)

__device__ __forceinline__ void proj_issue(
    const float* __restrict__ A, const float* __restrict__ W,
    int m0, int n0, int kt, int tid, float4* a_st, float4* w_st)
{
#pragma unroll
    for (int it = 0; it < 4; ++it) {
        const int flat = it * 256 + tid;   // 0..1023
        const int row  = flat >> 3;        // 0..127
        const int k4   = flat & 7;         // chunk of 4 floats
        a_st[it] = *(const float4*)(A + (size_t)(m0 + row) * 1024 + kt * BK + k4 * 4);
        w_st[it] = *(const float4*)(W + (size_t)(n0 + row) * 1024 + kt * BK + k4 * 4);
    }
}

__device__ __forceinline__ void proj_stage(
    const float4* a_st, const float4* w_st, int tid,
    bf16_t Al[BM][LDK], bf16_t Bl[BN][LDK])
{
#pragma unroll
    for (int it = 0; it < 4; ++it) {
        const int flat = it * 256 + tid;
        const int row  = flat >> 3;
        const int k4   = flat & 7;
        bf16x4 ab;
        ab[0] = (bf16_t)a_st[it].x; ab[1] = (bf16_t)a_st[it].y;
        ab[2] = (bf16_t)a_st[it].z; ab[3] = (bf16_t)a_st[it].w;
        *(bf16x4*)(&Al[row][k4 * 4]) = ab;
        bf16x4 wb;
        wb[0] = (bf16_t)w_st[it].x; wb[1] = (bf16_t)w_st[it].y;
        wb[2] = (bf16_t)w_st[it].z; wb[3] = (bf16_t)w_st[it].w;
        *(bf16x4*)(&Bl[row][k4 * 4]) = wb;
    }
}

__device__ __forceinline__ void proj_mma(
    const bf16_t Al[BM][LDK], const bf16_t Bl[BN][LDK],
    int wm, int wn, int lr, int lg, f32x4 acc[4][4])
{
    bf16x8 af[4], bfv[4];
#pragma unroll
    for (int i = 0; i < 4; ++i)
        af[i] = *(const bf16x8*)(&Al[wm + i * 16 + lr][lg * 8]);
#pragma unroll
    for (int j = 0; j < 4; ++j)
        bfv[j] = *(const bf16x8*)(&Bl[wn + j * 16 + lr][lg * 8]);
#pragma unroll
    for (int i = 0; i < 4; ++i)
#pragma unroll
        for (int j = 0; j < 4; ++j)
            acc[i][j] = MFMA16(af[i], bfv[j], acc[i][j]);
}

__global__ __launch_bounds__(256) void proj_kernel(
    const float* __restrict__ q_in, const float* __restrict__ k_in,
    const float* __restrict__ v_in, const float* __restrict__ Wk,
    const float* __restrict__ bk, const float* __restrict__ Wv,
    const float* __restrict__ bv, bf16_t* __restrict__ q_o,
    bf16_t* __restrict__ k_o, bf16_t* __restrict__ vt_o)
{
    const int z = blockIdx.z;
    const float* A    = (z == 0) ? q_in : (z == 1) ? k_in : v_in;
    const float* W    = (z == 2) ? Wv : Wk;
    const float* bias = (z == 2) ? bv : bk;

    __shared__ bf16_t Al[BM][LDK];
    __shared__ bf16_t Bl[BN][LDK];

    const int tid  = threadIdx.x;
    const int wv_  = tid >> 6;
    const int lane = tid & 63;
    const int lr   = lane & 15;
    const int lg   = lane >> 4;
    const int wm   = (wv_ >> 1) * 64;
    const int wn   = (wv_ & 1) * 64;
    const int m0   = blockIdx.x * BM;
    const int n0   = blockIdx.y * BN;

    f32x4 acc[4][4];
#pragma unroll
    for (int i = 0; i < 4; ++i)
#pragma unroll
        for (int j = 0; j < 4; ++j) acc[i][j] = (f32x4){0.f, 0.f, 0.f, 0.f};

    float4 aA[4], wA[4], aB[4], wB[4];
    proj_issue(A, W, m0, n0, 0, tid, aA, wA);

#pragma unroll 1
    for (int kp = 0; kp < 16; ++kp) {
        // even step 2kp: prefetch 2kp+1 into B-regs, consume A-regs
        proj_issue(A, W, m0, n0, 2 * kp + 1, tid, aB, wB);
        proj_stage(aA, wA, tid, Al, Bl);      // waits vmcnt(8): A-regs ready, B in flight
        __syncthreads();
        proj_mma(Al, Bl, wm, wn, lr, lg, acc);
        __syncthreads();
        // odd step 2kp+1: prefetch 2kp+2 into A-regs, consume B-regs
        if (kp < 15) proj_issue(A, W, m0, n0, 2 * kp + 2, tid, aA, wA);
        proj_stage(aB, wB, tid, Al, Bl);
        __syncthreads();
        proj_mma(Al, Bl, wm, wn, lr, lg, acc);
        __syncthreads();
    }

    // ---- epilogue: bias add, bf16 cast, head-split store ----
#pragma unroll
    for (int j = 0; j < 4; ++j) {
        const int ncol = n0 + wn + j * 16 + lr;
        const float bj = bias[ncol];
        const int h = ncol >> 6;
        const int d = ncol & 63;
#pragma unroll
        for (int i = 0; i < 4; ++i) {
            const int mrow0 = m0 + wm + i * 16 + lg * 4;
            f32x4 v = acc[i][j];
            if (z <= 1) {
                bf16_t* dst = (z == 0) ? q_o : k_o;
#pragma unroll
                for (int r = 0; r < 4; ++r) {
                    int m = mrow0 + r;
                    int b = m >> 10, s = m & 1023;
                    dst[(((size_t)(b * NH_ + h) << 10) + s) * HD_ + d] = (bf16_t)(v[r] + bj);
                }
            } else {
                int b = mrow0 >> 10, s = mrow0 & 1023;
                bf16x4 pk;
#pragma unroll
                for (int r = 0; r < 4; ++r) pk[r] = (bf16_t)(v[r] + bj);
                *(bf16x4*)(&vt_o[(((size_t)(b * NH_ + h) * HD_ + d) << 10) + s]) = pk;
            }
        }
    }
}

// ---------------------------------------------------------------------------
// Flash attention: per block = one 64-row q-tile of one (b,h).
// 4 waves, wave w owns 16 q-rows. KV tiles of 64 keys.
// q,k: [b][h][s][d] bf16 ; vt: [b][h][d][s] bf16 ; out f32 [b][s][h*64+d].
// No barriers -> waves drift out of phase -> setprio(1) around MFMA pays
// (T5, m191 regime).
// ---------------------------------------------------------------------------
__global__ __launch_bounds__(256) void attn_kernel(
    const bf16_t* __restrict__ q, const bf16_t* __restrict__ k,
    const bf16_t* __restrict__ vt, const int* __restrict__ mask,
    float* __restrict__ out)
{
    __shared__ bf16_t Pl[4][16][72];   // per-wave P tile, stride 72 (16B-aligned rows)

    const int bid = blockIdx.x;
    const int qt = bid & 15;
    const int bh = bid >> 4;
    const int b  = bh >> 4;
    const int h  = bh & 15;
    const int tid  = threadIdx.x;
    const int w    = tid >> 6;
    const int lane = tid & 63;
    const int lr   = lane & 15;
    const int lg   = lane >> 4;
    const int q0   = qt * 64 + w * 16;

    const bf16_t* qh = q  + ((size_t)bh << 16);
    const bf16_t* kh = k  + ((size_t)bh << 16);
    const bf16_t* vh = vt + ((size_t)bh << 16);
    const int*    mk = mask + b * S_;

    const bf16_t* qp = qh + (size_t)(q0 + lr) * HD_ + lg * 8;
    const bf16x8 qa0 = *(const bf16x8*)(qp);
    const bf16x8 qa1 = *(const bf16x8*)(qp + 32);

    f32x4 acc[4];
#pragma unroll
    for (int ds = 0; ds < 4; ++ds) acc[ds] = (f32x4){0.f, 0.f, 0.f, 0.f};
    float mrow[4] = {-30000.f, -30000.f, -30000.f, -30000.f};
    float lsum[4] = {0.f, 0.f, 0.f, 0.f};

#pragma unroll 1
    for (int t = 0; t < S_ / 64; ++t) {
        const int kb = t * 64;
        // ---- QK^T : scores for 64 keys ----
        f32x4 sc[4];
#pragma unroll
        for (int s4 = 0; s4 < 4; ++s4) {
            const bf16_t* kp = kh + (size_t)(kb + s4 * 16 + lr) * HD_ + lg * 8;
            bf16x8 kb0 = *(const bf16x8*)(kp);
            bf16x8 kb1 = *(const bf16x8*)(kp + 32);
            f32x4 zf = (f32x4){0.f, 0.f, 0.f, 0.f};
            __builtin_amdgcn_s_setprio(1);
            zf = MFMA16(qa0, kb0, zf);
            zf = MFMA16(qa1, kb1, zf);
            __builtin_amdgcn_s_setprio(0);
            sc[s4] = zf;
        }
        // ---- mask + scale ----
#pragma unroll
        for (int s4 = 0; s4 < 4; ++s4) {
            const int mv = mk[kb + s4 * 16 + lr];
#pragma unroll
            for (int r = 0; r < 4; ++r)
                sc[s4][r] = mv ? sc[s4][r] * 0.125f : -60000.f;
        }
        // ---- online softmax (row reduce across 16 lanes) ----
#pragma unroll
        for (int r = 0; r < 4; ++r) {
            float tm = fmaxf(fmaxf(sc[0][r], sc[1][r]), fmaxf(sc[2][r], sc[3][r]));
            tm = fmaxf(tm, __shfl_xor(tm, 1));
            tm = fmaxf(tm, __shfl_xor(tm, 2));
            tm = fmaxf(tm, __shfl_xor(tm, 4));
            tm = fmaxf(tm, __shfl_xor(tm, 8));
            const float mn  = fmaxf(mrow[r], tm);
            const float fac = __expf(mrow[r] - mn);
            mrow[r] = mn;
            float ps = 0.f;
#pragma unroll
            for (int s4 = 0; s4 < 4; ++s4) {
                float p = __expf(sc[s4][r] - mn);
                sc[s4][r] = p;
                ps += p;
            }
            ps += __shfl_xor(ps, 1);
            ps += __shfl_xor(ps, 2);
            ps += __shfl_xor(ps, 4);
            ps += __shfl_xor(ps, 8);
            lsum[r] = lsum[r] * fac + ps;
#pragma unroll
            for (int ds = 0; ds < 4; ++ds) acc[ds][r] *= fac;
        }
        // ---- P -> LDS (D-layout -> A-layout transpose) ----
#pragma unroll
        for (int s4 = 0; s4 < 4; ++s4)
#pragma unroll
            for (int r = 0; r < 4; ++r)
                Pl[w][lg * 4 + r][s4 * 16 + lr] = (bf16_t)sc[s4][r];

        // ---- PV ----
        const bf16x8 pa0 = *(const bf16x8*)(&Pl[w][lr][lg * 8]);
        const bf16x8 pa1 = *(const bf16x8*)(&Pl[w][lr][32 + lg * 8]);
#pragma unroll
        for (int ds = 0; ds < 4; ++ds) {
            const bf16_t* vp = vh + (size_t)(ds * 16 + lr) * S_ + kb + lg * 8;
            bf16x8 vb0 = *(const bf16x8*)(vp);
            bf16x8 vb1 = *(const bf16x8*)(vp + 32);
            __builtin_amdgcn_s_setprio(1);
            acc[ds] = MFMA16(pa0, vb0, acc[ds]);
            acc[ds] = MFMA16(pa1, vb1, acc[ds]);
            __builtin_amdgcn_s_setprio(0);
        }
    }

    // ---- normalize + store f32 out [b][s][h*64+d] ----
    float* ob = out + ((size_t)(b * S_ + q0)) * HID_ + h * HD_;
#pragma unroll
    for (int r = 0; r < 4; ++r) {
        const float inv = 1.0f / lsum[r];
#pragma unroll
        for (int ds = 0; ds < 4; ++ds)
            ob[(size_t)(lg * 4 + r) * HID_ + ds * 16 + lr] = acc[ds][r] * inv;
    }
}

extern "C" void kernel_launch(void* const* d_in, const int* in_sizes, int n_in,
                              void* d_out, int out_size, void* d_ws, size_t ws_size,
                              hipStream_t stream) {
    const float* key_in = (const float*)d_in[0];
    const float* val_in = (const float*)d_in[1];
    const float* qry_in = (const float*)d_in[2];
    const int*   mask   = (const int*)d_in[3];
    const float* Wk     = (const float*)d_in[4];
    const float* bk     = (const float*)d_in[5];
    const float* Wv     = (const float*)d_in[6];
    const float* bv     = (const float*)d_in[7];
    float* out = (float*)d_out;

    const size_t per = (size_t)B_ * NH_ * S_ * HD_;   // 8.39M bf16 elems
    bf16_t* q_ws  = (bf16_t*)d_ws;
    bf16_t* k_ws  = q_ws + per;
    bf16_t* vt_ws = k_ws + per;

    dim3 pg(8192 / BM, 1024 / BN, 3);
    proj_kernel<<<pg, 256, 0, stream>>>(qry_in, key_in, val_in, Wk, bk, Wv, bv,
                                        q_ws, k_ws, vt_ws);
    attn_kernel<<<B_ * NH_ * (S_ / 64), 256, 0, stream>>>(q_ws, k_ws, vt_ws, mask, out);
}

// Round 6
// 411.132 us; speedup vs baseline: 1.1571x; 1.1571x over previous
//
#include <hip/hip_runtime.h>
#include <hip/hip_bf16.h>
#include <stdint.h>

#define B_   8
#define S_   1024
#define HID_ 1024
#define NH_  16
#define HD_  64

typedef __bf16 bf16_t;
typedef __bf16 bf16x8 __attribute__((ext_vector_type(8)));
typedef __bf16 bf16x4 __attribute__((ext_vector_type(4)));
typedef __bf16 bf16x2 __attribute__((ext_vector_type(2)));
typedef float  f32x4  __attribute__((ext_vector_type(4)));
typedef float  f32x16 __attribute__((ext_vector_type(16)));
typedef uint32_t u32x4 __attribute__((ext_vector_type(4)));

#define MFMA16(a,b,c) __builtin_amdgcn_mfma_f32_16x16x32_bf16(a,b,c,0,0,0)
#define MFMA32(a,b,c) __builtin_amdgcn_mfma_f32_32x32x16_bf16(a,b,c,0,0,0)

typedef const __attribute__((address_space(1))) void* as1_t;
typedef __attribute__((address_space(3))) void* as3_t;
#define GLD16(g, s) __builtin_amdgcn_global_load_lds((as1_t)(g), (as3_t)(s), 16, 0, 0)

__device__ __forceinline__ float fexp2(float x) {
#if __has_builtin(__builtin_amdgcn_exp2f)
    return __builtin_amdgcn_exp2f(x);
#else
    return exp2f(x);
#endif
}

// pack two f32 -> one u32 of 2 bf16 (compiler picks cvt+pack; m240: don't hand-asm)
__device__ __forceinline__ uint32_t pk2(float a, float b) {
    bf16x2 v; v[0] = (bf16_t)a; v[1] = (bf16_t)b;
    return __builtin_bit_cast(uint32_t, v);
}

// ---------------------------------------------------------------------------
// Prepass: f32 -> bf16 vectorized convert
// ---------------------------------------------------------------------------
__global__ void conv_kernel(const float* __restrict__ src, bf16_t* __restrict__ dst, int n8) {
    int i = blockIdx.x * 256 + threadIdx.x;
    const int stride = gridDim.x * 256;
    for (; i < n8; i += stride) {
        const float4 a = ((const float4*)src)[2 * i];
        const float4 b = ((const float4*)src)[2 * i + 1];
        bf16x8 o;
        o[0] = (bf16_t)a.x; o[1] = (bf16_t)a.y; o[2] = (bf16_t)a.z; o[3] = (bf16_t)a.w;
        o[4] = (bf16_t)b.x; o[5] = (bf16_t)b.y; o[6] = (bf16_t)b.z; o[7] = (bf16_t)b.w;
        ((bf16x8*)dst)[i] = o;
    }
}

__global__ void maskbias_kernel(const int* __restrict__ mask, float* __restrict__ bias, int n) {
    const int i = blockIdx.x * 256 + threadIdx.x;
    if (i < n) bias[i] = mask[i] ? 0.f : -60000.f;
}

// ---------------------------------------------------------------------------
// Projection GEMM (bf16 in): C = A @ W^T + bias. 128x128 tile, BK=64,
// global_load_lds staging (m97 structure). XCD-grouped: xcd owns one 128-col
// W slice (L2-resident).
// Z=0: query@Wk+bk scaled by 0.125*log2(e) -> q_ws [8192][1024]
// Z=1: key  @Wk+bk                         -> k_ws [8192][1024]
// Z=2: value@Wv+bv                         -> vt_ws[b][h][d][s] (transposed)
// ---------------------------------------------------------------------------
template<int Z>
__global__ __launch_bounds__(256) void proj_kernel(
    const bf16_t* __restrict__ A, const bf16_t* __restrict__ W,
    const float* __restrict__ bias, bf16_t* __restrict__ dst)
{
    __shared__ bf16_t Al[128][64];
    __shared__ bf16_t Bl[128][64];

    const int bid = blockIdx.x;
    const int n0  = (bid & 7) * 128;           // xcd-grouped n-tile
    const int m0  = (bid >> 3) * 128;          // 0..63

    const int tid = threadIdx.x, w = tid >> 6, lane = tid & 63;
    const int lr = lane & 15, lg = lane >> 4;
    const int wm = (w >> 1) * 64, wn = (w & 1) * 64;
    const int srow = lane >> 3, scol = (lane & 7) * 8;

    f32x4 acc[4][4];
#pragma unroll
    for (int i = 0; i < 4; ++i)
#pragma unroll
        for (int j = 0; j < 4; ++j) acc[i][j] = (f32x4){0.f, 0.f, 0.f, 0.f};

#pragma unroll 1
    for (int kt = 0; kt < 16; ++kt) {
        const int k0 = kt * 64;
#pragma unroll
        for (int j = 0; j < 4; ++j) {
            const int flat = w * 4 + j;        // 16 instrs stage 128 rows each
            GLD16(A + (size_t)(m0 + flat * 8 + srow) * 1024 + k0 + scol,
                  (uint8_t*)Al + flat * 1024);
            GLD16(W + (size_t)(n0 + flat * 8 + srow) * 1024 + k0 + scol,
                  (uint8_t*)Bl + flat * 1024);
        }
        __syncthreads();
#pragma unroll
        for (int kk = 0; kk < 2; ++kk) {
            bf16x8 af[4], bfr[4];
#pragma unroll
            for (int i = 0; i < 4; ++i)
                af[i] = *(const bf16x8*)(&Al[wm + i * 16 + lr][kk * 32 + lg * 8]);
#pragma unroll
            for (int j = 0; j < 4; ++j)
                bfr[j] = *(const bf16x8*)(&Bl[wn + j * 16 + lr][kk * 32 + lg * 8]);
#pragma unroll
            for (int i = 0; i < 4; ++i)
#pragma unroll
                for (int j = 0; j < 4; ++j)
                    acc[i][j] = MFMA16(af[i], bfr[j], acc[i][j]);
        }
        __syncthreads();
    }

    const float qscale = 0.18033688011112042f;   // 0.125 * log2(e)
#pragma unroll
    for (int j = 0; j < 4; ++j) {
        const int ncol = n0 + wn + j * 16 + lr;
        const float bj = bias[ncol];
#pragma unroll
        for (int i = 0; i < 4; ++i) {
            const int m = m0 + wm + i * 16 + lg * 4;
            f32x4 v = acc[i][j];
            if (Z == 0) {
#pragma unroll
                for (int r = 0; r < 4; ++r)
                    dst[(size_t)(m + r) * 1024 + ncol] = (bf16_t)((v[r] + bj) * qscale);
            } else if (Z == 1) {
#pragma unroll
                for (int r = 0; r < 4; ++r)
                    dst[(size_t)(m + r) * 1024 + ncol] = (bf16_t)(v[r] + bj);
            } else {
                const int h = ncol >> 6, d = ncol & 63;
                const int b = m >> 10, s0 = m & 1023;
                bf16x4 pk;
#pragma unroll
                for (int r = 0; r < 4; ++r) pk[r] = (bf16_t)(v[r] + bj);
                *(bf16x4*)(&dst[((size_t)(b * 16 + h) * 64 + d) * 1024 + s0]) = pk;
            }
        }
    }
}

// ---------------------------------------------------------------------------
// Flash attention, swapped-QK^T 32x32, register-only softmax.
// All cross-lane ops via __shfl_xor / __shfl (unambiguous semantics).
// accP[r] = S[key = kb + crow(r,hi)][query = q0+lq],
//   crow(r,hi) = (r&3) + 8*(r>>2) + 4*hi   (m74/m101-verified C/D mapping)
// ---------------------------------------------------------------------------
__global__ __launch_bounds__(256) void attn_kernel(
    const bf16_t* __restrict__ qw, const bf16_t* __restrict__ kw,
    const bf16_t* __restrict__ vt, const float* __restrict__ mb,
    float* __restrict__ out)
{
    const int bid  = blockIdx.x;
    const int xcd  = bid & 7;                 // co-locate each bh's blocks
    const int slot = bid >> 3;                // 0..127
    const int bh   = xcd * 16 + (slot & 15);
    const int qt   = slot >> 4;               // 0..7
    const int b = bh >> 4, h = bh & 15;
    const int tid = threadIdx.x, w = tid >> 6, lane = tid & 63;
    const int lq = lane & 31, hi = lane >> 5;
    const int q0 = qt * 128 + w * 32;

    // Q B-frags: lane holds Q[q0+lq][c*16 + hi*8 + e]
    const bf16_t* qrow = qw + (size_t)(b * 1024 + q0 + lq) * 1024 + h * 64 + hi * 8;
    bf16x8 qf[4];
#pragma unroll
    for (int c = 0; c < 4; ++c) qf[c] = *(const bf16x8*)(qrow + c * 16);

    const bf16_t* kbase = kw + (size_t)(b * 1024) * 1024 + h * 64 + hi * 8;
    const bf16_t* vbase = vt + ((size_t)bh << 16) + (size_t)lq * 1024 + hi * 8;
    const float*  bb    = mb + b * 1024 + hi * 4;

    f32x16 accO0 = (f32x16)0.f, accO1 = (f32x16)0.f;
    float mrun = -30000.f, lrun = 0.f;

#pragma unroll 1
    for (int t = 0; t < 32; ++t) {
        const int kb = t * 32;
        f32x4 bias4[4];
#pragma unroll
        for (int g = 0; g < 4; ++g) bias4[g] = *(const f32x4*)(bb + kb + g * 8);
        bf16x8 kf[4];
#pragma unroll
        for (int c = 0; c < 4; ++c)
            kf[c] = *(const bf16x8*)(kbase + (size_t)(kb + lq) * 1024 + c * 16);
        const bf16x8 vf00 = *(const bf16x8*)(vbase + kb);
        const bf16x8 vf01 = *(const bf16x8*)(vbase + kb + 16);
        const bf16x8 vf10 = *(const bf16x8*)(vbase + 32 * 1024 + kb);
        const bf16x8 vf11 = *(const bf16x8*)(vbase + 32 * 1024 + kb + 16);

        // QK^T with mask bias as C-init (bias indexed by key = crow(r,hi))
        f32x16 accP;
#pragma unroll
        for (int r = 0; r < 16; ++r) accP[r] = bias4[r >> 2][r & 3];
        __builtin_amdgcn_s_setprio(1);
#pragma unroll
        for (int c = 0; c < 4; ++c) accP = MFMA32(kf[c], qf[c], accP);
        __builtin_amdgcn_s_setprio(0);

        // row max: in-lane tree over 16 regs + cross-half shfl_xor
        float x0 = fmaxf(accP[0], accP[1]),   x1 = fmaxf(accP[2], accP[3]);
        float x2 = fmaxf(accP[4], accP[5]),   x3 = fmaxf(accP[6], accP[7]);
        float x4 = fmaxf(accP[8], accP[9]),   x5 = fmaxf(accP[10], accP[11]);
        float x6 = fmaxf(accP[12], accP[13]), x7 = fmaxf(accP[14], accP[15]);
        x0 = fmaxf(x0, x1); x2 = fmaxf(x2, x3); x4 = fmaxf(x4, x5); x6 = fmaxf(x6, x7);
        x0 = fmaxf(x0, x2); x4 = fmaxf(x4, x6);
        float tm = fmaxf(x0, x4);
        tm = fmaxf(tm, __shfl_xor(tm, 32));

        // defer-max rescale (T13, thr=8 in exp2 domain -> P <= 256)
        if (!__all(tm <= mrun + 8.f)) {
            const float mn  = fmaxf(mrun, tm);
            const float fac = fexp2(mrun - mn);
            mrun = mn;
            lrun *= fac;
#pragma unroll
            for (int r = 0; r < 16; ++r) {
                const float fr = __shfl(fac, (r & 3) + 8 * (r >> 2) + 4 * hi, 64);
                accO0[r] *= fr; accO1[r] *= fr;
            }
        }

        // p = exp2(s - m), row sum
#pragma unroll
        for (int r = 0; r < 16; ++r) accP[r] = fexp2(accP[r] - mrun);
        float s0 = accP[0] + accP[1],   s1 = accP[2] + accP[3];
        float s2 = accP[4] + accP[5],   s3 = accP[6] + accP[7];
        float s4 = accP[8] + accP[9],   s5 = accP[10] + accP[11];
        float s6 = accP[12] + accP[13], s7 = accP[14] + accP[15];
        s0 += s1; s2 += s3; s4 += s5; s6 += s7;
        s0 += s2; s4 += s6;
        float ps = s0 + s4;
        ps += __shfl_xor(ps, 32);
        lrun += ps;

        // P -> bf16 A-frags. Lane (lq,hi) reg r holds key crow(r,hi); A-frag
        // word pattern: pa0 = keys {8hi+0..7}, pa1 = keys {16+8hi+0..7}.
        //   own packs:  c0={4hi,4hi+1} c1={4hi+2,4hi+3} c2={8+4hi,..} c3={10+4hi,..}
        //               c4={16+4hi,..} c5 c6={24+4hi,..} c7
        //   partner (shfl_xor 32) supplies the other half's packs.
        const uint32_t c0 = pk2(accP[0],  accP[1]),  c1 = pk2(accP[2],  accP[3]);
        const uint32_t c2 = pk2(accP[4],  accP[5]),  c3 = pk2(accP[6],  accP[7]);
        const uint32_t c4 = pk2(accP[8],  accP[9]),  c5 = pk2(accP[10], accP[11]);
        const uint32_t c6 = pk2(accP[12], accP[13]), c7 = pk2(accP[14], accP[15]);
        const uint32_t s0u = __shfl_xor(c0, 32), s1u = __shfl_xor(c1, 32);
        const uint32_t s2u = __shfl_xor(c2, 32), s3u = __shfl_xor(c3, 32);
        const uint32_t s4u = __shfl_xor(c4, 32), s5u = __shfl_xor(c5, 32);
        const uint32_t s6u = __shfl_xor(c6, 32), s7u = __shfl_xor(c7, 32);
        const u32x4 A0 = hi ? (u32x4){s2u, s3u, c2, c3} : (u32x4){c0, c1, s0u, s1u};
        const u32x4 A1 = hi ? (u32x4){s6u, s7u, c6, c7} : (u32x4){c4, c5, s4u, s5u};
        const bf16x8 pa0 = __builtin_bit_cast(bf16x8, A0);
        const bf16x8 pa1 = __builtin_bit_cast(bf16x8, A1);

        // PV: O[q][d] += P[q][k] * V[k][d]  (vf from vt => B[k=hi*8+e][d=lq])
        __builtin_amdgcn_s_setprio(1);
        accO0 = MFMA32(pa0, vf00, accO0);
        accO0 = MFMA32(pa1, vf01, accO0);
        accO1 = MFMA32(pa0, vf10, accO1);
        accO1 = MFMA32(pa1, vf11, accO1);
        __builtin_amdgcn_s_setprio(0);
    }

    // epilogue: normalize (stats live in lane lq for query lq), store f32
    const float inv = 1.f / lrun;
    float* ob = out + (size_t)b * 1048576 + h * 64;
#pragma unroll
    for (int r = 0; r < 16; ++r) {
        const int qr = (r & 3) + 8 * (r >> 2) + 4 * hi;
        const float ir = __shfl(inv, qr, 64);
        ob[(size_t)(q0 + qr) * 1024 + lq]      = accO0[r] * ir;
        ob[(size_t)(q0 + qr) * 1024 + 32 + lq] = accO1[r] * ir;
    }
}

extern "C" void kernel_launch(void* const* d_in, const int* in_sizes, int n_in,
                              void* d_out, int out_size, void* d_ws, size_t ws_size,
                              hipStream_t stream) {
    const float* key_in = (const float*)d_in[0];
    const float* val_in = (const float*)d_in[1];
    const float* qry_in = (const float*)d_in[2];
    const int*   mask   = (const int*)d_in[3];
    const float* Wk     = (const float*)d_in[4];
    const float* bk     = (const float*)d_in[5];
    const float* Wv     = (const float*)d_in[6];
    const float* bv     = (const float*)d_in[7];
    float* out = (float*)d_out;

    uint8_t* base = (uint8_t*)d_ws;
    const size_t SZ_IN = (size_t)8192 * 1024 * 2;   // 16.78 MB bf16
    const size_t SZ_W  = (size_t)1024 * 1024 * 2;   // 2.10 MB
    bf16_t* q_ws  = (bf16_t*)(base);
    bf16_t* k_ws  = (bf16_t*)(base + SZ_IN);
    bf16_t* vt_ws = (bf16_t*)(base + 2 * SZ_IN);
    bf16_t* sbuf  = (bf16_t*)(base + 3 * SZ_IN);            // shared staging
    bf16_t* wkbf  = (bf16_t*)(base + 4 * SZ_IN);
    bf16_t* wvbf  = (bf16_t*)(base + 4 * SZ_IN + SZ_W);
    float*  mbias = (float*) (base + 4 * SZ_IN + 2 * SZ_W); // total 71.34 MB

    conv_kernel<<<512, 256, 0, stream>>>(Wk, wkbf, 131072);
    conv_kernel<<<512, 256, 0, stream>>>(Wv, wvbf, 131072);
    maskbias_kernel<<<32, 256, 0, stream>>>(mask, mbias, 8192);

    conv_kernel<<<1024, 256, 0, stream>>>(qry_in, sbuf, 1048576);
    proj_kernel<0><<<512, 256, 0, stream>>>(sbuf, wkbf, bk, q_ws);
    conv_kernel<<<1024, 256, 0, stream>>>(key_in, sbuf, 1048576);
    proj_kernel<1><<<512, 256, 0, stream>>>(sbuf, wkbf, bk, k_ws);
    conv_kernel<<<1024, 256, 0, stream>>>(val_in, sbuf, 1048576);
    proj_kernel<2><<<512, 256, 0, stream>>>(sbuf, wvbf, bv, vt_ws);

    attn_kernel<<<1024, 256, 0, stream>>>(q_ws, k_ws, vt_ws, mbias, out);
}

// Round 10
// 372.006 us; speedup vs baseline: 1.2788x; 1.1052x over previous
//
#include <hip/hip_runtime.h>
#include <hip/hip_bf16.h>
#include <stdint.h>

#define B_   8
#define S_   1024
#define HID_ 1024
#define NH_  16
#define HD_  64

typedef __bf16 bf16_t;
typedef __bf16 bf16x8 __attribute__((ext_vector_type(8)));
typedef __bf16 bf16x4 __attribute__((ext_vector_type(4)));
typedef __bf16 bf16x2 __attribute__((ext_vector_type(2)));
typedef float  f32x4  __attribute__((ext_vector_type(4)));
typedef float  f32x16 __attribute__((ext_vector_type(16)));
typedef uint32_t u32x4 __attribute__((ext_vector_type(4)));

#define MFMA16(a,b,c) __builtin_amdgcn_mfma_f32_16x16x32_bf16(a,b,c,0,0,0)
#define MFMA32(a,b,c) __builtin_amdgcn_mfma_f32_32x32x16_bf16(a,b,c,0,0,0)

typedef const __attribute__((address_space(1))) void* as1_t;
typedef __attribute__((address_space(3))) void* as3_t;
#define GLD16(g, s) __builtin_amdgcn_global_load_lds((as1_t)(g), (as3_t)(s), 16, 0, 0)

__device__ __forceinline__ float fexp2(float x) {
#if __has_builtin(__builtin_amdgcn_exp2f)
    return __builtin_amdgcn_exp2f(x);
#else
    return exp2f(x);
#endif
}

__device__ __forceinline__ uint32_t pk2(float a, float b) {
    bf16x2 v; v[0] = (bf16_t)a; v[1] = (bf16_t)b;
    return __builtin_bit_cast(uint32_t, v);
}

// ---------------------------------------------------------------------------
// Prepass: f32 -> bf16 vectorized convert
// ---------------------------------------------------------------------------
__global__ void conv_kernel(const float* __restrict__ src, bf16_t* __restrict__ dst, int n8) {
    int i = blockIdx.x * 256 + threadIdx.x;
    const int stride = gridDim.x * 256;
    for (; i < n8; i += stride) {
        const float4 a = ((const float4*)src)[2 * i];
        const float4 b = ((const float4*)src)[2 * i + 1];
        bf16x8 o;
        o[0] = (bf16_t)a.x; o[1] = (bf16_t)a.y; o[2] = (bf16_t)a.z; o[3] = (bf16_t)a.w;
        o[4] = (bf16_t)b.x; o[5] = (bf16_t)b.y; o[6] = (bf16_t)b.z; o[7] = (bf16_t)b.w;
        ((bf16x8*)dst)[i] = o;
    }
}

__global__ void maskbias_kernel(const int* __restrict__ mask, float* __restrict__ bias, int n) {
    const int i = blockIdx.x * 256 + threadIdx.x;
    if (i < n) bias[i] = mask[i] ? 0.f : -60000.f;
}

// ---------------------------------------------------------------------------
// Projection GEMM helpers: 128x128 tile, BK=32, double-buffered LDS (T3
// minimum-2-phase: stage(t+1) issued BEFORE mma(t); single __syncthreads per
// step drains the prefetch under the compute). BK=32 -> each frag ds_read
// covers its full 1024B subtile => LDS-BW-optimal, no swizzle needed.
// ---------------------------------------------------------------------------
__device__ __forceinline__ void proj_stage(
    const bf16_t* __restrict__ A, const bf16_t* __restrict__ W,
    bf16_t (*Al)[32], bf16_t (*Bl)[32],
    int m0, int n0, int k0, int w, int lane)
{
#pragma unroll
    for (int j = 0; j < 2; ++j) {
        const int ia  = w * 2 + j;              // 0..7 wave-instrs each for A,B
        const int row = ia * 16 + (lane >> 2);
        const int ce  = (lane & 3) * 8;
        GLD16(A + (size_t)(m0 + row) * 1024 + k0 + ce, (uint8_t*)Al + ia * 1024);
        GLD16(W + (size_t)(n0 + row) * 1024 + k0 + ce, (uint8_t*)Bl + ia * 1024);
    }
}

__device__ __forceinline__ void proj_mma(
    const bf16_t (*Al)[32], const bf16_t (*Bl)[32],
    int wm, int wn, int lr, int lg, f32x4 acc[4][4])
{
    bf16x8 af[4], bfr[4];
#pragma unroll
    for (int i = 0; i < 4; ++i)
        af[i] = *(const bf16x8*)(&Al[wm + i * 16 + lr][lg * 8]);
#pragma unroll
    for (int j = 0; j < 4; ++j)
        bfr[j] = *(const bf16x8*)(&Bl[wn + j * 16 + lr][lg * 8]);
#pragma unroll
    for (int i = 0; i < 4; ++i)
#pragma unroll
        for (int j = 0; j < 4; ++j)
            acc[i][j] = MFMA16(af[i], bfr[j], acc[i][j]);
}

// q/k projections merged: 1024 blocks (4/CU). z = slot&1 (interleaved).
__global__ __launch_bounds__(256) void proj01_kernel(
    const bf16_t* __restrict__ qstage, const bf16_t* __restrict__ kstage,
    const bf16_t* __restrict__ wk, const float* __restrict__ bk,
    bf16_t* __restrict__ q_ws, bf16_t* __restrict__ k_ws)
{
    __shared__ bf16_t Al[2][128][32];
    __shared__ bf16_t Bl[2][128][32];

    const int bid  = blockIdx.x;
    const int n0   = (bid & 7) * 128;          // xcd-grouped n-tile
    const int slot = bid >> 3;                 // 0..127
    const int z    = slot & 1;
    const int m0   = (slot >> 1) * 128;
    const bf16_t* A = z ? kstage : qstage;
    bf16_t* dst     = z ? k_ws : q_ws;

    const int tid = threadIdx.x, w = tid >> 6, lane = tid & 63;
    const int lr = lane & 15, lg = lane >> 4;
    const int wm = (w >> 1) * 64, wn = (w & 1) * 64;

    f32x4 acc[4][4];
#pragma unroll
    for (int i = 0; i < 4; ++i)
#pragma unroll
        for (int j = 0; j < 4; ++j) acc[i][j] = (f32x4){0.f, 0.f, 0.f, 0.f};

    proj_stage(A, wk, Al[0], Bl[0], m0, n0, 0, w, lane);
    __syncthreads();
#pragma unroll 1
    for (int kt = 0; kt < 32; kt += 2) {
        proj_stage(A, wk, Al[1], Bl[1], m0, n0, (kt + 1) * 32, w, lane);
        proj_mma(Al[0], Bl[0], wm, wn, lr, lg, acc);
        __syncthreads();
        if (kt + 2 < 32) proj_stage(A, wk, Al[0], Bl[0], m0, n0, (kt + 2) * 32, w, lane);
        proj_mma(Al[1], Bl[1], wm, wn, lr, lg, acc);
        __syncthreads();
    }

    const float scale = z ? 1.0f : 0.18033688011112042f;   // q: 0.125*log2(e)
#pragma unroll
    for (int j = 0; j < 4; ++j) {
        const int ncol = n0 + wn + j * 16 + lr;
        const float bj = bk[ncol];
#pragma unroll
        for (int i = 0; i < 4; ++i) {
            const int m = m0 + wm + i * 16 + lg * 4;
            f32x4 v = acc[i][j];
#pragma unroll
            for (int r = 0; r < 4; ++r)
                dst[(size_t)(m + r) * 1024 + ncol] = (bf16_t)((v[r] + bj) * scale);
        }
    }
}

// value projection -> vt_ws[b][h][d][s] (transposed for attn PV B-operand)
__global__ __launch_bounds__(256) void proj2_kernel(
    const bf16_t* __restrict__ vstage, const bf16_t* __restrict__ wv,
    const float* __restrict__ bv, bf16_t* __restrict__ vt_ws)
{
    __shared__ bf16_t Al[2][128][32];
    __shared__ bf16_t Bl[2][128][32];

    const int bid = blockIdx.x;
    const int n0  = (bid & 7) * 128;
    const int m0  = (bid >> 3) * 128;

    const int tid = threadIdx.x, w = tid >> 6, lane = tid & 63;
    const int lr = lane & 15, lg = lane >> 4;
    const int wm = (w >> 1) * 64, wn = (w & 1) * 64;

    f32x4 acc[4][4];
#pragma unroll
    for (int i = 0; i < 4; ++i)
#pragma unroll
        for (int j = 0; j < 4; ++j) acc[i][j] = (f32x4){0.f, 0.f, 0.f, 0.f};

    proj_stage(vstage, wv, Al[0], Bl[0], m0, n0, 0, w, lane);
    __syncthreads();
#pragma unroll 1
    for (int kt = 0; kt < 32; kt += 2) {
        proj_stage(vstage, wv, Al[1], Bl[1], m0, n0, (kt + 1) * 32, w, lane);
        proj_mma(Al[0], Bl[0], wm, wn, lr, lg, acc);
        __syncthreads();
        if (kt + 2 < 32) proj_stage(vstage, wv, Al[0], Bl[0], m0, n0, (kt + 2) * 32, w, lane);
        proj_mma(Al[1], Bl[1], wm, wn, lr, lg, acc);
        __syncthreads();
    }

#pragma unroll
    for (int j = 0; j < 4; ++j) {
        const int ncol = n0 + wn + j * 16 + lr;
        const float bj = bv[ncol];
        const int h = ncol >> 6, d = ncol & 63;
#pragma unroll
        for (int i = 0; i < 4; ++i) {
            const int m = m0 + wm + i * 16 + lg * 4;
            const int b = m >> 10, s0 = m & 1023;
            f32x4 v = acc[i][j];
            bf16x4 pk;
#pragma unroll
            for (int r = 0; r < 4; ++r) pk[r] = (bf16_t)(v[r] + bj);
            *(bf16x4*)(&vt_ws[((size_t)(b * 16 + h) * 64 + d) * 1024 + s0]) = pk;
        }
    }
}

// ---------------------------------------------------------------------------
// Flash attention, swapped-QK^T 32x32, register-only softmax, with 2-deep
// K-prefetch pipeline (only K's load latency is exposed: QK^T consumes it
// immediately; V/bias are consumed hundreds of cycles after issue).
// Mask bias staged once into LDS (4KB) -> frees 24 held VGPRs.
// ---------------------------------------------------------------------------
__global__ __launch_bounds__(256) void attn_kernel(
    const bf16_t* __restrict__ qw, const bf16_t* __restrict__ kw,
    const bf16_t* __restrict__ vt, const float* __restrict__ mb,
    float* __restrict__ out)
{
    __shared__ float bl[1024];

    const int bid  = blockIdx.x;
    const int xcd  = bid & 7;
    const int slot = bid >> 3;                // 0..127
    const int bh   = xcd * 16 + (slot & 15);  // 8 q-tiles of one bh share an XCD
    const int qt   = slot >> 4;               // 0..7
    const int b = bh >> 4, h = bh & 15;
    const int tid = threadIdx.x, w = tid >> 6, lane = tid & 63;
    const int lq = lane & 31, hi = lane >> 5;
    const int q0 = qt * 128 + w * 32;

    // stage mask-bias row for this batch (256 threads x 16B = 4KB)
    ((f32x4*)bl)[tid] = ((const f32x4*)(mb + (size_t)b * 1024))[tid];
    __syncthreads();

    const bf16_t* qrow = qw + (size_t)(b * 1024 + q0 + lq) * 1024 + h * 64 + hi * 8;
    bf16x8 qf[4];
#pragma unroll
    for (int c = 0; c < 4; ++c) qf[c] = *(const bf16x8*)(qrow + c * 16);

    const bf16_t* kbase = kw + (size_t)(b * 1024) * 1024 + h * 64 + hi * 8;
    const bf16_t* vbase = vt + ((size_t)bh << 16) + (size_t)lq * 1024 + hi * 8;

    f32x16 accO0 = (f32x16)0.f, accO1 = (f32x16)0.f;
    float mrun = -30000.f, lrun = 0.f;

    auto LOADK = [&](bf16x8 (&kf)[4], int t) {
        const int kb = t * 32;
#pragma unroll
        for (int c = 0; c < 4; ++c)
            kf[c] = *(const bf16x8*)(kbase + (size_t)(kb + lq) * 1024 + c * 16);
    };

    auto PROCESS = [&](const bf16x8 (&kf)[4], int t) {
        const int kb = t * 32;
        // V loads + bias ds_reads issue here; consumed after QK^T+softmax
        const bf16x8 vf00 = *(const bf16x8*)(vbase + kb);
        const bf16x8 vf01 = *(const bf16x8*)(vbase + kb + 16);
        const bf16x8 vf10 = *(const bf16x8*)(vbase + 32 * 1024 + kb);
        const bf16x8 vf11 = *(const bf16x8*)(vbase + 32 * 1024 + kb + 16);
        f32x4 bias4[4];
#pragma unroll
        for (int g = 0; g < 4; ++g)
            bias4[g] = *(const f32x4*)(&bl[kb + g * 8 + hi * 4]);

        f32x16 accP = (f32x16)0.f;
        __builtin_amdgcn_s_setprio(1);
#pragma unroll
        for (int c = 0; c < 4; ++c) accP = MFMA32(kf[c], qf[c], accP);
        __builtin_amdgcn_s_setprio(0);
        // additive mask (bias indexed by key = crow(r,hi))
#pragma unroll
        for (int r = 0; r < 16; ++r) accP[r] += bias4[r >> 2][r & 3];

        // row max: in-lane tree + cross-half shfl
        float x0 = fmaxf(accP[0], accP[1]),   x1 = fmaxf(accP[2], accP[3]);
        float x2 = fmaxf(accP[4], accP[5]),   x3 = fmaxf(accP[6], accP[7]);
        float x4 = fmaxf(accP[8], accP[9]),   x5 = fmaxf(accP[10], accP[11]);
        float x6 = fmaxf(accP[12], accP[13]), x7 = fmaxf(accP[14], accP[15]);
        x0 = fmaxf(x0, x1); x2 = fmaxf(x2, x3); x4 = fmaxf(x4, x5); x6 = fmaxf(x6, x7);
        x0 = fmaxf(x0, x2); x4 = fmaxf(x4, x6);
        float tm = fmaxf(x0, x4);
        tm = fmaxf(tm, __shfl_xor(tm, 32));

        // defer-max rescale (T13)
        if (!__all(tm <= mrun + 8.f)) {
            const float mn  = fmaxf(mrun, tm);
            const float fac = fexp2(mrun - mn);
            mrun = mn;
            lrun *= fac;
#pragma unroll
            for (int r = 0; r < 16; ++r) {
                const float fr = __shfl(fac, (r & 3) + 8 * (r >> 2) + 4 * hi, 64);
                accO0[r] *= fr; accO1[r] *= fr;
            }
        }

        // p = exp2(s - m), row sum
#pragma unroll
        for (int r = 0; r < 16; ++r) accP[r] = fexp2(accP[r] - mrun);
        float s0 = accP[0] + accP[1],   s1 = accP[2] + accP[3];
        float s2 = accP[4] + accP[5],   s3 = accP[6] + accP[7];
        float s4 = accP[8] + accP[9],   s5 = accP[10] + accP[11];
        float s6 = accP[12] + accP[13], s7 = accP[14] + accP[15];
        s0 += s1; s2 += s3; s4 += s5; s6 += s7;
        s0 += s2; s4 += s6;
        float ps = s0 + s4;
        ps += __shfl_xor(ps, 32);
        lrun += ps;

        // P -> bf16 A-frags (pack + cross-half shfl + select)
        const uint32_t c0 = pk2(accP[0],  accP[1]),  c1 = pk2(accP[2],  accP[3]);
        const uint32_t c2 = pk2(accP[4],  accP[5]),  c3 = pk2(accP[6],  accP[7]);
        const uint32_t c4 = pk2(accP[8],  accP[9]),  c5 = pk2(accP[10], accP[11]);
        const uint32_t c6 = pk2(accP[12], accP[13]), c7 = pk2(accP[14], accP[15]);
        const uint32_t s0u = __shfl_xor(c0, 32), s1u = __shfl_xor(c1, 32);
        const uint32_t s2u = __shfl_xor(c2, 32), s3u = __shfl_xor(c3, 32);
        const uint32_t s4u = __shfl_xor(c4, 32), s5u = __shfl_xor(c5, 32);
        const uint32_t s6u = __shfl_xor(c6, 32), s7u = __shfl_xor(c7, 32);
        const u32x4 A0 = hi ? (u32x4){s2u, s3u, c2, c3} : (u32x4){c0, c1, s0u, s1u};
        const u32x4 A1 = hi ? (u32x4){s6u, s7u, c6, c7} : (u32x4){c4, c5, s4u, s5u};
        const bf16x8 pa0 = __builtin_bit_cast(bf16x8, A0);
        const bf16x8 pa1 = __builtin_bit_cast(bf16x8, A1);

        __builtin_amdgcn_s_setprio(1);
        accO0 = MFMA32(pa0, vf00, accO0);
        accO0 = MFMA32(pa1, vf01, accO0);
        accO1 = MFMA32(pa0, vf10, accO1);
        accO1 = MFMA32(pa1, vf11, accO1);
        __builtin_amdgcn_s_setprio(0);
    };

    bf16x8 kfA[4], kfB[4];
    LOADK(kfA, 0);
#pragma unroll 1
    for (int t = 0; t < 32; t += 2) {
        LOADK(kfB, t + 1);                 // issued before PROCESS(A) -> hidden
        PROCESS(kfA, t);
        if (t + 2 < 32) LOADK(kfA, t + 2); // issued before PROCESS(B) -> hidden
        PROCESS(kfB, t + 1);
    }

    const float inv = 1.f / lrun;
    float* ob = out + (size_t)b * 1048576 + h * 64;
#pragma unroll
    for (int r = 0; r < 16; ++r) {
        const int qr = (r & 3) + 8 * (r >> 2) + 4 * hi;
        const float ir = __shfl(inv, qr, 64);
        ob[(size_t)(q0 + qr) * 1024 + lq]      = accO0[r] * ir;
        ob[(size_t)(q0 + qr) * 1024 + 32 + lq] = accO1[r] * ir;
    }
}

extern "C" void kernel_launch(void* const* d_in, const int* in_sizes, int n_in,
                              void* d_out, int out_size, void* d_ws, size_t ws_size,
                              hipStream_t stream) {
    const float* key_in = (const float*)d_in[0];
    const float* val_in = (const float*)d_in[1];
    const float* qry_in = (const float*)d_in[2];
    const int*   mask   = (const int*)d_in[3];
    const float* Wk     = (const float*)d_in[4];
    const float* bk     = (const float*)d_in[5];
    const float* Wv     = (const float*)d_in[6];
    const float* bv     = (const float*)d_in[7];
    float* out = (float*)d_out;

    uint8_t* base = (uint8_t*)d_ws;
    const size_t SZ_IN = (size_t)8192 * 1024 * 2;   // 16.78 MB bf16
    const size_t SZ_W  = (size_t)1024 * 1024 * 2;   // 2.10 MB
    bf16_t* q_ws  = (bf16_t*)(base);
    bf16_t* k_ws  = (bf16_t*)(base + SZ_IN);
    bf16_t* vt_ws = (bf16_t*)(base + 2 * SZ_IN);    // holds staged key until proj2
    bf16_t* sbuf  = (bf16_t*)(base + 3 * SZ_IN);    // staged query, then value
    bf16_t* wkbf  = (bf16_t*)(base + 4 * SZ_IN);
    bf16_t* wvbf  = (bf16_t*)(base + 4 * SZ_IN + SZ_W);
    float*  mbias = (float*) (base + 4 * SZ_IN + 2 * SZ_W); // total 71.34 MB

    conv_kernel<<<512, 256, 0, stream>>>(Wk, wkbf, 131072);
    conv_kernel<<<512, 256, 0, stream>>>(Wv, wvbf, 131072);
    maskbias_kernel<<<32, 256, 0, stream>>>(mask, mbias, 8192);

    conv_kernel<<<1024, 256, 0, stream>>>(qry_in, sbuf, 1048576);
    conv_kernel<<<1024, 256, 0, stream>>>(key_in, (bf16_t*)vt_ws, 1048576);
    proj01_kernel<<<1024, 256, 0, stream>>>(sbuf, (const bf16_t*)vt_ws, wkbf, bk,
                                            q_ws, k_ws);
    conv_kernel<<<1024, 256, 0, stream>>>(val_in, sbuf, 1048576);
    proj2_kernel<<<512, 256, 0, stream>>>(sbuf, wvbf, bv, vt_ws);

    attn_kernel<<<1024, 256, 0, stream>>>(q_ws, k_ws, vt_ws, mbias, out);
}